// Round 4
// baseline (1091.907 us; speedup 1.0000x reference)
//
#include <hip/hip_runtime.h>
#include <hip/hip_fp16.h>

#define B_ 256
#define T_ 512
#define D_ 64
#define H_ 128
#define BB 16  // batches per recurrent block

typedef float f32x4 __attribute__((ext_vector_type(4)));
typedef short s16x4 __attribute__((ext_vector_type(4)));
typedef short s16x8 __attribute__((ext_vector_type(8)));
typedef __bf16 bf16x8 __attribute__((ext_vector_type(8)));
typedef _Float16 h16x4 __attribute__((ext_vector_type(4)));

template <typename AT> __device__ inline AT toAT(float x);
template <> __device__ inline float toAT<float>(float x) { return x; }
template <> __device__ inline __half toAT<__half>(float x) { return __float2half(x); }

template <typename AT> struct V4 {};
template <> struct V4<float> { typedef f32x4 type; };
template <> struct V4<__half> { typedef h16x4 type; };

__device__ inline float fsig(float x) {
  return __builtin_amdgcn_rcpf(1.f + __expf(-x));
}
__device__ inline float ftanh(float x) {
  return 1.f - 2.f * __builtin_amdgcn_rcpf(1.f + __expf(2.f * x));
}
__device__ inline short f2bf(float f) {  // RNE float->bf16
  unsigned u = __builtin_bit_cast(unsigned, f);
  u += 0x7fff + ((u >> 16) & 1);
  return (short)(u >> 16);
}

// ---------------------------------------------------------------------------
// Kernel 1 (unchanged): per-(b,t) pre-activations, layout A[row][4][H]
//   gate 0: G = exp(-relu(dlt @ w_gamma_h + b_gamma_h)) (pre-exponentiated)
//   gate 1: A_z, gate 2: A_r, gate 3: A_h
// ---------------------------------------------------------------------------
template <typename AT>
__global__ __launch_bounds__(256) void grud_pre(
    const float* __restrict__ values, const float* __restrict__ masks,
    const float* __restrict__ deltas, const float* __restrict__ emean,
    const float* __restrict__ locf,
    const float* __restrict__ w_gamma_x, const float* __restrict__ w_gamma_h,
    const float* __restrict__ w_rx, const float* __restrict__ w_rm,
    const float* __restrict__ w_zx, const float* __restrict__ w_zm,
    const float* __restrict__ w_hx, const float* __restrict__ w_hm,
    const float* __restrict__ b_gamma_x, const float* __restrict__ b_gamma_h,
    const float* __restrict__ b_r, const float* __restrict__ b_z,
    const float* __restrict__ b_h, AT* __restrict__ A) {
  __shared__ __align__(16) float xs[64][64];
  __shared__ __align__(16) float ms_[64][64];
  __shared__ float c_wg[64], c_bg[64], c_mn[64];

  const int tid = threadIdx.x;
  const int gate = blockIdx.y;
  const int rowbase = blockIdx.x * 64;
  const size_t base = (size_t)rowbase * D_;

  if (gate == 0) {
    const float4* dp = (const float4*)(deltas + base);
    for (int i = tid; i < 1024; i += 256) ((float4*)&xs[0][0])[i] = dp[i];
  } else {
    if (tid < 64) {
      c_wg[tid] = w_gamma_x[tid];
      c_bg[tid] = b_gamma_x[tid];
      c_mn[tid] = emean[tid];
    }
    __syncthreads();
    const float4* vp = (const float4*)(values + base);
    const float4* mp = (const float4*)(masks + base);
    const float4* dp = (const float4*)(deltas + base);
    const float4* lp = (const float4*)(locf + base);
    for (int i = tid; i < 1024; i += 256) {
      float4 v = vp[i], m = mp[i], dl = dp[i], l = lp[i];
      const int d0 = (i & 15) * 4;
      float vv[4] = {v.x, v.y, v.z, v.w};
      float mm[4] = {m.x, m.y, m.z, m.w};
      float dd[4] = {dl.x, dl.y, dl.z, dl.w};
      float ll[4] = {l.x, l.y, l.z, l.w};
      float xo[4];
#pragma unroll
      for (int j = 0; j < 4; ++j) {
        const int d = d0 + j;
        float gx = __expf(-fmaxf(c_wg[d] * dd[j] + c_bg[d], 0.f));
        xo[j] = mm[j] * vv[j] + (1.f - mm[j]) * (gx * ll[j] + (1.f - gx) * c_mn[d]);
      }
      ((float4*)&xs[0][0])[i] = make_float4(xo[0], xo[1], xo[2], xo[3]);
      ((float4*)&ms_[0][0])[i] = m;
    }
  }
  __syncthreads();

  const int col = tid & 127;
  const int rset = tid >> 7;
  const float* Wx;
  const float* Wm = nullptr;
  const float* bias;
  if (gate == 0) {
    Wx = w_gamma_h; bias = b_gamma_h;
  } else if (gate == 1) {
    Wx = w_zx; Wm = w_zm; bias = b_z;
  } else if (gate == 2) {
    Wx = w_rx; Wm = w_rm; bias = b_r;
  } else {
    Wx = w_hx; Wm = w_hm; bias = b_h;
  }

  float wx[64], wm[64];
#pragma unroll
  for (int k = 0; k < 64; ++k) wx[k] = Wx[k * H_ + col];
  if (gate != 0) {
#pragma unroll
    for (int k = 0; k < 64; ++k) wm[k] = Wm[k * H_ + col];
  }
  const float bv = bias[col];

  for (int r = 0; r < 32; ++r) {
    const int row = rset * 32 + r;
    float a0 = 0.f, a1 = 0.f, a2 = 0.f, a3 = 0.f;
    if (gate == 0) {
#pragma unroll
      for (int k4 = 0; k4 < 16; ++k4) {
        float4 xv = *(const float4*)&xs[row][k4 * 4];
        a0 += xv.x * wx[k4 * 4 + 0];
        a1 += xv.y * wx[k4 * 4 + 1];
        a2 += xv.z * wx[k4 * 4 + 2];
        a3 += xv.w * wx[k4 * 4 + 3];
      }
    } else {
#pragma unroll
      for (int k4 = 0; k4 < 16; ++k4) {
        float4 xv = *(const float4*)&xs[row][k4 * 4];
        float4 mv = *(const float4*)&ms_[row][k4 * 4];
        a0 += xv.x * wx[k4 * 4 + 0] + mv.x * wm[k4 * 4 + 0];
        a1 += xv.y * wx[k4 * 4 + 1] + mv.y * wm[k4 * 4 + 1];
        a2 += xv.z * wx[k4 * 4 + 2] + mv.z * wm[k4 * 4 + 2];
        a3 += xv.w * wx[k4 * 4 + 3] + mv.w * wm[k4 * 4 + 3];
      }
    }
    float acc = bv + ((a0 + a1) + (a2 + a3));
    if (gate == 0) acc = __expf(-fmaxf(acc, 0.f));
    A[(size_t)(rowbase + row) * (4 * H_) + gate * H_ + col] = toAT<AT>(acc);
  }
}

// ---------------------------------------------------------------------------
// Kernel 2: MFMA recurrence. 16 blocks x 16 batches, 512 threads (8 waves).
// Wave w owns output cols [w*16, w*16+16). Transposed matvec:
//   D[n][m] = sum_k W[k][n] * h[m][k]   (A-frag = W^T slice, static in VGPRs;
//   B-frag = h (bf16) staged in XOR-swizzled LDS)
// mfma_f32_16x16x32_bf16 layouts: A: [row=l&15][k=8*(l>>4)+j];
//   B: [k=8*(l>>4)+j][col=l&15]; D: [row=(l>>4)*4+j][col=l&15].
// Lane l => batch = l&15, cols = w*16 + (l>>4)*4 + j  (j=0..3).
// h kept fp32 in LDS (no compounding error); bf16 only as MFMA input.
// 2 barriers/step; A-row prefetch depth 2.
// ---------------------------------------------------------------------------
template <typename AT>
__global__ __launch_bounds__(512, 1) void grud_rec_mfma(
    const AT* __restrict__ A, const float* __restrict__ w_zh,
    const float* __restrict__ w_rh, const float* __restrict__ w_hh,
    float* __restrict__ hid, float* __restrict__ hlast) {
  const int tid = threadIdx.x;
  const int w = tid >> 6;
  const int lane = tid & 63;
  const int bql = lane & 15;  // batch (B/D) ; weight output-col row (A)
  const int lg = lane >> 4;   // 0..3
  const int nbase = w * 16;
  const int cb = nbase + lg * 4;  // first of this lane's 4 output cols
  const int bb = blockIdx.x * BB;
  const int bg = bb + bql;  // global batch for loads/stores

  __shared__ __align__(16) char lds[BB * 256 * 2 + BB * 512];
  char* h_bf = lds;          // [16][128] bf16, swizzled (4 KB)
  char* rh_bf = lds + 4096;  // [16][128] bf16, swizzled (4 KB)
  char* h_fp = lds + 8192;   // [16][128] fp32, swizzled (8 KB)

  // static weight A-frags: frag[tau], reg j = W[lg*8+j+32*tau][nbase+bql]
  s16x8 wz[4], wr[4], wh[4];
#pragma unroll
  for (int tau = 0; tau < 4; ++tau) {
    s16x8 az, ar, ah;
#pragma unroll
    for (int j = 0; j < 8; ++j) {
      const int k = lg * 8 + j + 32 * tau;
      az[j] = f2bf(w_zh[k * H_ + nbase + bql]);
      ar[j] = f2bf(w_rh[k * H_ + nbase + bql]);
      ah[j] = f2bf(w_hh[k * H_ + nbase + bql]);
    }
    wz[tau] = az; wr[tau] = ar; wh[tau] = ah;
  }

  // zero-init h state (h=0 at t=0; swizzle irrelevant for zeros)
  for (int i = tid; i < (int)sizeof(lds) / 16; i += 512)
    ((f32x4*)lds)[i] = f32x4{0.f, 0.f, 0.f, 0.f};

  // swizzled LDS byte offsets (lane constants)
  const int swz = (bql & 7) << 4;
  int off_rd[4];
#pragma unroll
  for (int tau = 0; tau < 4; ++tau)
    off_rd[tau] = bql * 256 + ((lg * 16 + tau * 64) ^ swz);
  const int off_bfw = bql * 256 + ((cb * 2) ^ swz);
  const int off_fp = bql * 512 + ((cb * 4) ^ swz);

  typedef typename V4<AT>::type v4t;
  const v4t* Arows = (const v4t*)A;
  const int ci = cb >> 2;  // v4 index within a 128-col gate block
  // row t, gate g vec4 index: ((bg*T + t)*4 + g)*32 + ci
  auto rowbase = [&](int t) { return ((size_t)bg * T_ + t) * 128 + ci; };

  v4t g0, cz, cr, ch, g1, nz, nr, nh;
  {
    size_t r0 = rowbase(0);
    g0 = Arows[r0]; cz = Arows[r0 + 32]; cr = Arows[r0 + 64]; ch = Arows[r0 + 96];
    size_t r1 = rowbase(T_ > 1 ? 1 : 0);
    g1 = Arows[r1]; nz = Arows[r1 + 32]; nr = Arows[r1 + 64]; nh = Arows[r1 + 96];
  }
  __syncthreads();

  for (int t = 0; t < T_; ++t) {
    // prefetch row t+2
    v4t g2, pz, pr, ph;
    {
      const int t2 = (t + 2 < T_) ? t + 2 : T_ - 1;
      size_t r2 = rowbase(t2);
      g2 = Arows[r2]; pz = Arows[r2 + 32]; pr = Arows[r2 + 64]; ph = Arows[r2 + 96];
    }

    // z/r matvecs over h_bf (shared B-frags)
    f32x4 Dz = {0.f, 0.f, 0.f, 0.f}, Dr = {0.f, 0.f, 0.f, 0.f};
#pragma unroll
    for (int tau = 0; tau < 4; ++tau) {
      s16x8 bh = *(const s16x8*)(h_bf + off_rd[tau]);
      Dz = __builtin_amdgcn_mfma_f32_16x16x32_bf16(
          __builtin_bit_cast(bf16x8, wz[tau]), __builtin_bit_cast(bf16x8, bh),
          Dz, 0, 0, 0);
      Dr = __builtin_amdgcn_mfma_f32_16x16x32_bf16(
          __builtin_bit_cast(bf16x8, wr[tau]), __builtin_bit_cast(bf16x8, bh),
          Dr, 0, 0, 0);
    }
    f32x4 hsc = *(const f32x4*)(h_fp + off_fp);

    f32x4 zz;
    s16x4 rhv;
#pragma unroll
    for (int j = 0; j < 4; ++j) {
      zz[j] = fsig((float)cz[j] + Dz[j]);
      float rr = fsig((float)cr[j] + Dr[j]);
      rhv[j] = f2bf(rr * hsc[j]);
    }
    *(s16x4*)(rh_bf + off_bfw) = rhv;
    __syncthreads();

    // h_tilde matvec over rh_bf
    f32x4 Dh = {0.f, 0.f, 0.f, 0.f};
#pragma unroll
    for (int tau = 0; tau < 4; ++tau) {
      s16x8 brh = *(const s16x8*)(rh_bf + off_rd[tau]);
      Dh = __builtin_amdgcn_mfma_f32_16x16x32_bf16(
          __builtin_bit_cast(bf16x8, wh[tau]), __builtin_bit_cast(bf16x8, brh),
          Dh, 0, 0, 0);
    }

    f32x4 hnv, hgv;
    s16x4 hbv;
#pragma unroll
    for (int j = 0; j < 4; ++j) {
      float ht = ftanh((float)ch[j] + Dh[j]);
      float hn = (1.f - zz[j]) * hsc[j] + zz[j] * ht;
      hnv[j] = hn;
      float hg = hn * (float)g1[j];  // fold gamma_h(t+1)
      hgv[j] = hg;
      hbv[j] = f2bf(hg);
    }
    *(f32x4*)(hid + ((size_t)bg * T_ + t) * H_ + cb) = hnv;
    if (t == T_ - 1) {
      *(f32x4*)(hlast + (size_t)bg * H_ + cb) = hnv;
    } else {
      *(f32x4*)(h_fp + off_fp) = hgv;
      *(s16x4*)(h_bf + off_bfw) = hbv;
    }
    cz = nz; cr = nr; ch = nh; g1 = g2; nz = pz; nr = pr; nh = ph;
    __syncthreads();
  }
}

extern "C" void kernel_launch(void* const* d_in, const int* in_sizes, int n_in,
                              void* d_out, int out_size, void* d_ws, size_t ws_size,
                              hipStream_t stream) {
  const float* values = (const float*)d_in[0];
  const float* masks = (const float*)d_in[1];
  const float* deltas = (const float*)d_in[2];
  const float* emean = (const float*)d_in[3];
  const float* locf = (const float*)d_in[4];
  const float* w_gamma_x = (const float*)d_in[5];
  const float* w_gamma_h = (const float*)d_in[6];
  const float* w_rx = (const float*)d_in[7];
  const float* w_rh = (const float*)d_in[8];
  const float* w_rm = (const float*)d_in[9];
  const float* w_zx = (const float*)d_in[10];
  const float* w_zh = (const float*)d_in[11];
  const float* w_zm = (const float*)d_in[12];
  const float* w_hx = (const float*)d_in[13];
  const float* w_hh = (const float*)d_in[14];
  const float* w_hm = (const float*)d_in[15];
  const float* b_gamma_x = (const float*)d_in[16];
  const float* b_gamma_h = (const float*)d_in[17];
  const float* b_r = (const float*)d_in[18];
  const float* b_z = (const float*)d_in[19];
  const float* b_h = (const float*)d_in[20];

  float* hid = (float*)d_out;
  float* hlast = hid + (size_t)B_ * T_ * H_;

  dim3 gpre(B_ * T_ / 64, 4), bpre(256);
  dim3 grec(B_ / BB), brec(512);

  const size_t needH = (size_t)B_ * T_ * 4 * H_ * sizeof(__half);
  const size_t needF = (size_t)B_ * T_ * 4 * H_ * sizeof(float);
  if (ws_size >= needH) {
    __half* A = (__half*)d_ws;
    grud_pre<__half><<<gpre, bpre, 0, stream>>>(
        values, masks, deltas, emean, locf, w_gamma_x, w_gamma_h, w_rx, w_rm,
        w_zx, w_zm, w_hx, w_hm, b_gamma_x, b_gamma_h, b_r, b_z, b_h, A);
    grud_rec_mfma<__half><<<grec, brec, 0, stream>>>(A, w_zh, w_rh, w_hh, hid,
                                                     hlast);
  } else if (ws_size >= needF) {
    float* A = (float*)d_ws;
    grud_pre<float><<<gpre, bpre, 0, stream>>>(
        values, masks, deltas, emean, locf, w_gamma_x, w_gamma_h, w_rx, w_rm,
        w_zx, w_zm, w_hx, w_hm, b_gamma_x, b_gamma_h, b_r, b_z, b_h, A);
    grud_rec_mfma<float><<<grec, brec, 0, stream>>>(A, w_zh, w_rh, w_hh, hid,
                                                    hlast);
  }
}